// Round 4
// baseline (402.808 us; speedup 1.0000x reference)
//
#include <hip/hip_runtime.h>
#include <hip/hip_bf16.h>

// ScalarQLinear via int8 MFMA, round 4:
//   - Double-buffered LDS K-loop (prefetch depth 1, 2x32 KB = 64 KB LDS).
//     Loads for tile t+1 issue BEFORE compute of tile t; the compiler's
//     mandatory vmcnt(0) drain at s_barrier then lands AFTER ~500 cyc of
//     compute instead of immediately after issue -> latency hidden.
//     One barrier per K-iter (32 total) instead of two (64).
//   - Keeps R3's XOR chunk swizzle (bank conflicts measured 0).
//   - BK=128, 128x128 tile, mfma_i32_16x16x64_i8, fused quantizers.

typedef int int32x4 __attribute__((ext_vector_type(4)));

#define MDIM 8192
#define NDIM 4096
#define KDIM 4096

__device__ __forceinline__ void async_copy16(const void* g, void* l) {
  __builtin_amdgcn_global_load_lds(
      (const __attribute__((address_space(1))) void*)g,
      (__attribute__((address_space(3))) void*)l, 16, 0, 0);
}

__device__ __forceinline__ unsigned pack4(float a, float b, float c, float d) {
  return ((unsigned)((int)a & 0xff)) | ((unsigned)((int)b & 0xff) << 8) |
         ((unsigned)((int)c & 0xff) << 16) | ((unsigned)((int)d & 0xff) << 24);
}

// --- K1: fused quantizers. Blocks [0,4096): w rows; [4096,12288): x rows. ---
__global__ __launch_bounds__(256) void quantize_all(
    const float* __restrict__ w, const float* __restrict__ x,
    unsigned* __restrict__ qw, unsigned* __restrict__ qx,
    float* __restrict__ scale, float* __restrict__ sx) {
  const int t = threadIdx.x;
  __shared__ float wred[4];
  if (blockIdx.x < NDIM) {
    const int row = blockIdx.x;
    const float4* wr = (const float4*)(w + (size_t)row * KDIM);
    float4 v[4];
    float ss = 0.f;
#pragma unroll
    for (int i = 0; i < 4; ++i) {
      v[i] = wr[t + 256 * i];
      ss += v[i].x * v[i].x + v[i].y * v[i].y + v[i].z * v[i].z + v[i].w * v[i].w;
    }
#pragma unroll
    for (int m = 32; m >= 1; m >>= 1) ss += __shfl_xor(ss, m, 64);
    if ((t & 63) == 0) wred[t >> 6] = ss;
    __syncthreads();
    const float safe = fmaxf(sqrtf(wred[0] + wred[1] + wred[2] + wred[3]), 1e-8f);
    unsigned* qr = qw + (size_t)row * (KDIM / 4);
#pragma unroll
    for (int i = 0; i < 4; ++i) {
      float q0 = fminf(fmaxf(rintf(v[i].x / safe * 60.0f), -8.f), 7.f);
      float q1 = fminf(fmaxf(rintf(v[i].y / safe * 60.0f), -8.f), 7.f);
      float q2 = fminf(fmaxf(rintf(v[i].z / safe * 60.0f), -8.f), 7.f);
      float q3 = fminf(fmaxf(rintf(v[i].w / safe * 60.0f), -8.f), 7.f);
      qr[t + 256 * i] = pack4(q0, q1, q2, q3);
    }
    if (t == 0) scale[row] = safe / 60.0f;
  } else {
    const int row = blockIdx.x - NDIM;
    const float4* xr = (const float4*)(x + (size_t)row * KDIM);
    float4 v[4];
    float am = 0.f;
#pragma unroll
    for (int i = 0; i < 4; ++i) {
      v[i] = xr[t + 256 * i];
      am = fmaxf(am, fmaxf(fmaxf(fabsf(v[i].x), fabsf(v[i].y)),
                           fmaxf(fabsf(v[i].z), fabsf(v[i].w))));
    }
#pragma unroll
    for (int m = 32; m >= 1; m >>= 1) am = fmaxf(am, __shfl_xor(am, m, 64));
    if ((t & 63) == 0) wred[t >> 6] = am;
    __syncthreads();
    const float amax =
        fmaxf(fmaxf(fmaxf(wred[0], wred[1]), fmaxf(wred[2], wred[3])), 1e-20f);
    const float r = 127.0f / amax;
    unsigned* qr = qx + (size_t)row * (KDIM / 4);
#pragma unroll
    for (int i = 0; i < 4; ++i) {
      float q0 = fminf(fmaxf(rintf(v[i].x * r), -127.f), 127.f);
      float q1 = fminf(fmaxf(rintf(v[i].y * r), -127.f), 127.f);
      float q2 = fminf(fmaxf(rintf(v[i].z * r), -127.f), 127.f);
      float q3 = fminf(fmaxf(rintf(v[i].w * r), -127.f), 127.f);
      qr[t + 256 * i] = pack4(q0, q1, q2, q3);
    }
    if (t == 0) sx[row] = amax / 127.0f;
  }
}

// --- K2: C[m,n] = sx[m]*scale[n]*dot_i8(A[m,:],B[n,:]) + bias[n] ---
// 128x128 tile, BK=128, double-buffered LDS, swizzled chunks.
__global__ __launch_bounds__(256) void gemm_i8(const char* __restrict__ A,
                                               const char* __restrict__ B,
                                               const float* __restrict__ sx,
                                               const float* __restrict__ scale,
                                               const float* __restrict__ bias,
                                               float* __restrict__ C) {
  __shared__ __align__(16) char sA[2][128 * 128];  // 32 KB
  __shared__ __align__(16) char sB[2][128 * 128];  // 32 KB
  const int tid = threadIdx.x;
  const int m0 = blockIdx.y * 128;
  const int n0 = blockIdx.x * 128;

  // staging: lane tid -> LDS slot (row = issue*32 + tid>>3, chunk = tid&7).
  // phys_chunk = logical_chunk ^ (row&7): fetch the permuted global chunk so
  // LDS lands pre-swizzled (global_load_lds is flat lane-order).
  const int r0 = tid >> 3;                              // 0..31
  const int c16 = ((tid & 7) ^ ((tid >> 3) & 7)) * 16;  // swizzled source col
  const char* gA = A + (size_t)(m0 + r0) * KDIM + c16;
  const char* gB = B + (size_t)(n0 + r0) * KDIM + c16;

  const int lane = tid & 63;
  const int wid = tid >> 6;
  const int wm = (wid & 1) * 64;
  const int wn = (wid >> 1) * 64;
  const int fr = lane & 15;  // A: m, B: n
  const int q = lane >> 4;   // k-quad
  const int sw = fr & 7;
  const int ph0 = ((q) ^ sw) * 16;      // phys chunk offset, k-half 0
  const int ph1 = ((4 + q) ^ sw) * 16;  // phys chunk offset, k-half 1

  int32x4 acc[4][4] = {};

#define ISSUE(p)                                                      \
  do {                                                                \
    _Pragma("unroll") for (int i = 0; i < 4; ++i) {                   \
      async_copy16(gA + (size_t)(32 * i) * KDIM,                      \
                   &sA[p][i * 4096] + tid * 16);                      \
      async_copy16(gB + (size_t)(32 * i) * KDIM,                      \
                   &sB[p][i * 4096] + tid * 16);                      \
    }                                                                 \
    gA += 128;                                                        \
    gB += 128;                                                        \
  } while (0)

#define COMPUTE(p)                                                    \
  do {                                                                \
    _Pragma("unroll") for (int h = 0; h < 2; ++h) {                   \
      const int ph = h ? ph1 : ph0;                                   \
      int32x4 af[4], bg[4];                                           \
      _Pragma("unroll") for (int i = 0; i < 4; ++i)                   \
          af[i] = *(const int32x4*)&sA[p][(wm + i * 16 + fr) * 128 + ph]; \
      _Pragma("unroll") for (int j = 0; j < 4; ++j)                   \
          bg[j] = *(const int32x4*)&sB[p][(wn + j * 16 + fr) * 128 + ph]; \
      _Pragma("unroll") for (int i = 0; i < 4; ++i)                   \
          _Pragma("unroll") for (int j = 0; j < 4; ++j)               \
              acc[i][j] = __builtin_amdgcn_mfma_i32_16x16x64_i8(      \
                  af[i], bg[j], acc[i][j], 0, 0, 0);                  \
    }                                                                 \
  } while (0)

  ISSUE(0);  // prologue: tile 0 -> buf0
  for (int kt = 0; kt < KDIM / 128; kt += 2) {  // 16 outer iters (32 tiles)
    __syncthreads();        // drains tile kt (buf0); all waves done with buf1
    ISSUE(1);               // tile kt+1 -> buf1, flies during compute
    COMPUTE(0);             // tile kt from buf0
    __syncthreads();        // drains tile kt+1; all waves done with buf0
    if (kt + 2 < KDIM / 128) ISSUE(0);  // tile kt+2 -> buf0
    COMPUTE(1);             // tile kt+1 from buf1
  }
#undef ISSUE
#undef COMPUTE

  // epilogue: C/D layout col = lane&15, row = quad*4 + reg (shape-determined)
  float scl[4], bs[4];
#pragma unroll
  for (int j = 0; j < 4; ++j) {
    const int n = n0 + wn + j * 16 + fr;
    scl[j] = scale[n];
    bs[j] = bias[n];
  }
  const int mrow = q * 4;
#pragma unroll
  for (int i = 0; i < 4; ++i) {
#pragma unroll
    for (int r = 0; r < 4; ++r) {
      const size_t m = (size_t)(m0 + wm + i * 16 + mrow + r);
      const float sxm = sx[m];
      float* crow = C + m * NDIM + (n0 + wn + fr);
#pragma unroll
      for (int j = 0; j < 4; ++j)
        crow[j * 16] = (float)acc[i][j][r] * (sxm * scl[j]) + bs[j];
    }
  }
}

extern "C" void kernel_launch(void* const* d_in, const int* in_sizes, int n_in,
                              void* d_out, int out_size, void* d_ws, size_t ws_size,
                              hipStream_t stream) {
  (void)in_sizes; (void)n_in; (void)out_size; (void)ws_size;
  const float* x = (const float*)d_in[0];     // [8192, 4096] fp32
  const float* w = (const float*)d_in[1];     // [4096, 4096] fp32
  const float* bias = (const float*)d_in[2];  // [4096] fp32
  float* out = (float*)d_out;                 // [8192, 4096] fp32

  char* ws = (char*)d_ws;
  char* qx = ws;                                           // 32 MB int8
  char* qw = ws + (size_t)33554432;                        // 16 MB int8
  float* sx = (float*)(ws + (size_t)50331648);             // 32 KB
  float* scale = (float*)(ws + (size_t)50331648 + 65536);  // 16 KB

  quantize_all<<<NDIM + MDIM, 256, 0, stream>>>(w, x, (unsigned*)qw,
                                                (unsigned*)qx, scale, sx);
  dim3 grid(NDIM / 128, MDIM / 128);  // (32, 64)
  gemm_i8<<<grid, 256, 0, stream>>>(qx, qw, sx, scale, bias, out);
}

// Round 5
// 376.853 us; speedup vs baseline: 1.0689x; 1.0689x over previous
//
#include <hip/hip_runtime.h>
#include <hip/hip_bf16.h>

// ScalarQLinear via int8 MFMA, round 5:
//   R4 post-mortem: explicit double-buffer regressed (156->170 us) — reverted.
//   R3 counters imply the LDS read pipe binds (8 waves x 16 ds_read_b128 x 12cy
//   = 1536 cy/CU/iter vs 1306 cy MFMA). Fix: bigger wave tile to cut LDS
//   bytes per MFMA op:
//   - Block tile 128x256 (M x N), 4 waves each 64x128 (acc 4x8).
//     LDS bytes/op drops 25% (15.6 -> 11.7 B/Kop); ops per barrier doubles.
//   - Single-buffered 2-barrier K-loop (R3 structure), BK=128, 48 KB LDS.
//   - XOR chunk swizzle kept (R3 measured 0 bank conflicts).
//   - mfma_i32_16x16x64_i8 (layouts verified in R2/R3), fused quantizers.

typedef int int32x4 __attribute__((ext_vector_type(4)));

#define MDIM 8192
#define NDIM 4096
#define KDIM 4096

__device__ __forceinline__ void async_copy16(const void* g, void* l) {
  __builtin_amdgcn_global_load_lds(
      (const __attribute__((address_space(1))) void*)g,
      (__attribute__((address_space(3))) void*)l, 16, 0, 0);
}

__device__ __forceinline__ unsigned pack4(float a, float b, float c, float d) {
  return ((unsigned)((int)a & 0xff)) | ((unsigned)((int)b & 0xff) << 8) |
         ((unsigned)((int)c & 0xff) << 16) | ((unsigned)((int)d & 0xff) << 24);
}

// --- K1: fused quantizers. Blocks [0,4096): w rows; [4096,12288): x rows. ---
__global__ __launch_bounds__(256) void quantize_all(
    const float* __restrict__ w, const float* __restrict__ x,
    unsigned* __restrict__ qw, unsigned* __restrict__ qx,
    float* __restrict__ scale, float* __restrict__ sx) {
  const int t = threadIdx.x;
  __shared__ float wred[4];
  if (blockIdx.x < NDIM) {
    const int row = blockIdx.x;
    const float4* wr = (const float4*)(w + (size_t)row * KDIM);
    float4 v[4];
    float ss = 0.f;
#pragma unroll
    for (int i = 0; i < 4; ++i) {
      v[i] = wr[t + 256 * i];
      ss += v[i].x * v[i].x + v[i].y * v[i].y + v[i].z * v[i].z + v[i].w * v[i].w;
    }
#pragma unroll
    for (int m = 32; m >= 1; m >>= 1) ss += __shfl_xor(ss, m, 64);
    if ((t & 63) == 0) wred[t >> 6] = ss;
    __syncthreads();
    const float safe = fmaxf(sqrtf(wred[0] + wred[1] + wred[2] + wred[3]), 1e-8f);
    unsigned* qr = qw + (size_t)row * (KDIM / 4);
#pragma unroll
    for (int i = 0; i < 4; ++i) {
      float q0 = fminf(fmaxf(rintf(v[i].x / safe * 60.0f), -8.f), 7.f);
      float q1 = fminf(fmaxf(rintf(v[i].y / safe * 60.0f), -8.f), 7.f);
      float q2 = fminf(fmaxf(rintf(v[i].z / safe * 60.0f), -8.f), 7.f);
      float q3 = fminf(fmaxf(rintf(v[i].w / safe * 60.0f), -8.f), 7.f);
      qr[t + 256 * i] = pack4(q0, q1, q2, q3);
    }
    if (t == 0) scale[row] = safe / 60.0f;
  } else {
    const int row = blockIdx.x - NDIM;
    const float4* xr = (const float4*)(x + (size_t)row * KDIM);
    float4 v[4];
    float am = 0.f;
#pragma unroll
    for (int i = 0; i < 4; ++i) {
      v[i] = xr[t + 256 * i];
      am = fmaxf(am, fmaxf(fmaxf(fabsf(v[i].x), fabsf(v[i].y)),
                           fmaxf(fabsf(v[i].z), fabsf(v[i].w))));
    }
#pragma unroll
    for (int m = 32; m >= 1; m >>= 1) am = fmaxf(am, __shfl_xor(am, m, 64));
    if ((t & 63) == 0) wred[t >> 6] = am;
    __syncthreads();
    const float amax =
        fmaxf(fmaxf(fmaxf(wred[0], wred[1]), fmaxf(wred[2], wred[3])), 1e-20f);
    const float r = 127.0f / amax;
    unsigned* qr = qx + (size_t)row * (KDIM / 4);
#pragma unroll
    for (int i = 0; i < 4; ++i) {
      float q0 = fminf(fmaxf(rintf(v[i].x * r), -127.f), 127.f);
      float q1 = fminf(fmaxf(rintf(v[i].y * r), -127.f), 127.f);
      float q2 = fminf(fmaxf(rintf(v[i].z * r), -127.f), 127.f);
      float q3 = fminf(fmaxf(rintf(v[i].w * r), -127.f), 127.f);
      qr[t + 256 * i] = pack4(q0, q1, q2, q3);
    }
    if (t == 0) sx[row] = amax / 127.0f;
  }
}

// --- K2: C[m,n] = sx[m]*scale[n]*dot_i8(A[m,:],B[n,:]) + bias[n] ---
// Block tile 128(M) x 256(N), BK=128; 4 waves each 64x128 (acc 4x8).
__global__ __launch_bounds__(256, 2) void gemm_i8(const char* __restrict__ A,
                                                  const char* __restrict__ B,
                                                  const float* __restrict__ sx,
                                                  const float* __restrict__ scale,
                                                  const float* __restrict__ bias,
                                                  float* __restrict__ C) {
  __shared__ __align__(16) char sA[128 * 128];  // 16 KB (x tile)
  __shared__ __align__(16) char sB[256 * 128];  // 32 KB (w tile)
  const int tid = threadIdx.x;
  const int m0 = blockIdx.y * 128;
  const int n0 = blockIdx.x * 256;

  // staging: lane tid -> LDS slot (row = issue*32 + tid>>3, chunk = tid&7);
  // phys_chunk = logical_chunk ^ (row&7) applied at the SOURCE.
  const int r0 = tid >> 3;                              // 0..31
  const int c16 = ((tid & 7) ^ ((tid >> 3) & 7)) * 16;  // swizzled source col
  const char* gA = A + (size_t)(m0 + r0) * KDIM + c16;
  const char* gB = B + (size_t)(n0 + r0) * KDIM + c16;
  char* lA = sA + tid * 16;
  char* lB = sB + tid * 16;

  const int lane = tid & 63;
  const int wid = tid >> 6;
  const int wm = (wid & 1) * 64;    // wave M offset: 0 / 64
  const int wn = (wid >> 1) * 128;  // wave N offset: 0 / 128
  const int fr = lane & 15;  // A: m, B: n
  const int q = lane >> 4;   // k-quad
  const int sw = fr & 7;
  const int ph0 = ((q) ^ sw) * 16;      // phys chunk offset, k-half 0
  const int ph1 = ((4 + q) ^ sw) * 16;  // phys chunk offset, k-half 1

  int32x4 acc[4][8] = {};

  for (int kt = 0; kt < KDIM / 128; ++kt) {  // 32 iterations
    __syncthreads();  // prior-iter LDS reads done before overwrite
#pragma unroll
    for (int i = 0; i < 4; ++i)
      async_copy16(gA + (size_t)(32 * i) * KDIM, lA + i * 4096);
#pragma unroll
    for (int i = 0; i < 8; ++i)
      async_copy16(gB + (size_t)(32 * i) * KDIM, lB + i * 4096);
    __syncthreads();  // vmcnt(0) drain + barrier
    gA += 128; gB += 128;

#pragma unroll
    for (int h = 0; h < 2; ++h) {
      const int ph = h ? ph1 : ph0;
      int32x4 af[4], bg[8];
#pragma unroll
      for (int i = 0; i < 4; ++i)
        af[i] = *(const int32x4*)&sA[(wm + i * 16 + fr) * 128 + ph];
#pragma unroll
      for (int j = 0; j < 8; ++j)
        bg[j] = *(const int32x4*)&sB[(wn + j * 16 + fr) * 128 + ph];
#pragma unroll
      for (int i = 0; i < 4; ++i)
#pragma unroll
        for (int j = 0; j < 8; ++j)
          acc[i][j] =
              __builtin_amdgcn_mfma_i32_16x16x64_i8(af[i], bg[j], acc[i][j], 0, 0, 0);
    }
  }

  // epilogue: C/D layout col = lane&15, row = quad*4 + reg (shape-determined)
  float scl[8], bs[8];
#pragma unroll
  for (int j = 0; j < 8; ++j) {
    const int n = n0 + wn + j * 16 + fr;
    scl[j] = scale[n];
    bs[j] = bias[n];
  }
  const int mrow = q * 4;
#pragma unroll
  for (int i = 0; i < 4; ++i) {
#pragma unroll
    for (int r = 0; r < 4; ++r) {
      const size_t m = (size_t)(m0 + wm + i * 16 + mrow + r);
      const float sxm = sx[m];
      float* crow = C + m * NDIM + (n0 + wn + fr);
#pragma unroll
      for (int j = 0; j < 8; ++j)
        crow[j * 16] = (float)acc[i][j][r] * (sxm * scl[j]) + bs[j];
    }
  }
}

extern "C" void kernel_launch(void* const* d_in, const int* in_sizes, int n_in,
                              void* d_out, int out_size, void* d_ws, size_t ws_size,
                              hipStream_t stream) {
  (void)in_sizes; (void)n_in; (void)out_size; (void)ws_size;
  const float* x = (const float*)d_in[0];     // [8192, 4096] fp32
  const float* w = (const float*)d_in[1];     // [4096, 4096] fp32
  const float* bias = (const float*)d_in[2];  // [4096] fp32
  float* out = (float*)d_out;                 // [8192, 4096] fp32

  char* ws = (char*)d_ws;
  char* qx = ws;                                           // 32 MB int8
  char* qw = ws + (size_t)33554432;                        // 16 MB int8
  float* sx = (float*)(ws + (size_t)50331648);             // 32 KB
  float* scale = (float*)(ws + (size_t)50331648 + 65536);  // 16 KB

  quantize_all<<<NDIM + MDIM, 256, 0, stream>>>(w, x, (unsigned*)qw,
                                                (unsigned*)qx, scale, sx);
  dim3 grid(NDIM / 256, MDIM / 128);  // (16, 64)
  gemm_i8<<<grid, 256, 0, stream>>>(qx, qw, sx, scale, bias, out);
}